// Round 1
// baseline (2609.009 us; speedup 1.0000x reference)
//
#include <hip/hip_runtime.h>
#include <hip/hip_bf16.h>

// GIN 3-layer forward on MI355X (gfx950).
// Structure per layer: h2 = h + segment_sum(h[src], dst); relu(h2@W1+b1)@W2+b2.
// Implementation: CSR build (hist+scan+scatter) once per call, reused by 3
// aggregation passes; fp32 LDS-tiled GEMM (no fp32 MFMA on CDNA4 -> VALU).

#define DIN 128
#define DH  256

// ---------------------------------------------------------------- CSR build
__global__ __launch_bounds__(256) void k_zero(int* p, int n) {
    int i = blockIdx.x * 256 + threadIdx.x;
    if (i < n) p[i] = 0;
}

__global__ __launch_bounds__(256) void k_hist(const int* __restrict__ dst,
                                              int* __restrict__ cnt, int E) {
    int e = blockIdx.x * 256 + threadIdx.x;
    if (e < E) atomicAdd(&cnt[dst[e]], 1);
}

// Per-block inclusive scan (Hillis-Steele), writes exclusive result + block sum.
__global__ __launch_bounds__(1024) void k_scan1(const int* __restrict__ cnt,
                                                int* __restrict__ rp,
                                                int* __restrict__ bsum, int n) {
    __shared__ int tmp[1024];
    int tid = threadIdx.x;
    int gid = blockIdx.x * 1024 + tid;
    int v = (gid < n) ? cnt[gid] : 0;
    tmp[tid] = v;
    __syncthreads();
    for (int off = 1; off < 1024; off <<= 1) {
        int add = (tid >= off) ? tmp[tid - off] : 0;
        __syncthreads();
        tmp[tid] += add;
        __syncthreads();
    }
    if (gid < n) rp[gid] = tmp[tid] - v;          // exclusive within block
    if (tid == 1023) bsum[blockIdx.x] = tmp[tid]; // block total
}

__global__ void k_scan2(const int* __restrict__ bsum, int* __restrict__ boff, int nb) {
    if (threadIdx.x == 0 && blockIdx.x == 0) {
        int s = 0;
        for (int i = 0; i < nb; ++i) { boff[i] = s; s += bsum[i]; }
    }
}

__global__ __launch_bounds__(1024) void k_scan3(int* __restrict__ rp,
                                                int* __restrict__ cur,
                                                const int* __restrict__ boff,
                                                int n, int E) {
    int gid = blockIdx.x * 1024 + threadIdx.x;
    if (gid < n) {
        int v = rp[gid] + boff[blockIdx.x];
        rp[gid]  = v;
        cur[gid] = v;
    }
    if (gid == 0) rp[n] = E;
}

__global__ __launch_bounds__(256) void k_scatter(const int* __restrict__ src,
                                                 const int* __restrict__ dst,
                                                 int* __restrict__ cur,
                                                 int* __restrict__ csr, int E) {
    int e = blockIdx.x * 256 + threadIdx.x;
    if (e < E) {
        int pos = atomicAdd(&cur[dst[e]], 1);
        csr[pos] = src[e];
    }
}

// ------------------------------------------------------------- aggregation
// out[i] = h[i] + sum_{j in-neighbors(i)} h[j].  One wave per node.
__global__ __launch_bounds__(256) void k_agg256(const float* __restrict__ H,
                                                const int* __restrict__ rp,
                                                const int* __restrict__ csr,
                                                float* __restrict__ out, int n) {
    int node = (int)((blockIdx.x * 256 + threadIdx.x) >> 6);
    if (node >= n) return;
    int lane = threadIdx.x & 63;
    size_t off = (size_t)node * DH + lane * 4;
    float4 acc = *(const float4*)(H + off);       // self term (eps = 0)
    int p = rp[node], pe = rp[node + 1];
    for (; p + 1 < pe; p += 2) {
        int j0 = csr[p], j1 = csr[p + 1];
        float4 a = *(const float4*)(H + (size_t)j0 * DH + lane * 4);
        float4 b = *(const float4*)(H + (size_t)j1 * DH + lane * 4);
        acc.x += a.x + b.x; acc.y += a.y + b.y;
        acc.z += a.z + b.z; acc.w += a.w + b.w;
    }
    if (p < pe) {
        int j = csr[p];
        float4 a = *(const float4*)(H + (size_t)j * DH + lane * 4);
        acc.x += a.x; acc.y += a.y; acc.z += a.z; acc.w += a.w;
    }
    *(float4*)(out + off) = acc;
}

__global__ __launch_bounds__(256) void k_agg128(const float* __restrict__ H,
                                                const int* __restrict__ rp,
                                                const int* __restrict__ csr,
                                                float* __restrict__ out, int n) {
    int node = (int)((blockIdx.x * 256 + threadIdx.x) >> 6);
    if (node >= n) return;
    int lane = threadIdx.x & 63;
    size_t off = (size_t)node * DIN + lane * 2;
    float2 acc = *(const float2*)(H + off);
    int p = rp[node], pe = rp[node + 1];
    for (; p + 1 < pe; p += 2) {
        int j0 = csr[p], j1 = csr[p + 1];
        float2 a = *(const float2*)(H + (size_t)j0 * DIN + lane * 2);
        float2 b = *(const float2*)(H + (size_t)j1 * DIN + lane * 2);
        acc.x += a.x + b.x; acc.y += a.y + b.y;
    }
    if (p < pe) {
        int j = csr[p];
        float2 a = *(const float2*)(H + (size_t)j * DIN + lane * 2);
        acc.x += a.x; acc.y += a.y;
    }
    *(float2*)(out + off) = acc;
}

// ------------------------------------------------------------------- GEMM
// C[M x 256] = A[M x K] @ W[K x 256] + bias, optional relu.
// Block: 256 threads -> 32 rows x 256 cols tile. Thread: 8 rows x 4 cols.
// Per k-step/thread: 32 v_fma_f32 vs 3 ds_read_b128 -> VALU-bound.
template<int K, bool RELU>
__global__ __launch_bounds__(256) void k_gemm(const float* __restrict__ A,
                                              const float* __restrict__ W,
                                              const float* __restrict__ bias,
                                              float* __restrict__ C, int M) {
    __shared__ __align__(16) float As[32][36];   // [kk][row], pad 36 vs conflicts
    __shared__ __align__(16) float Ws[32][256];  // [kk][col]

    const int t    = threadIdx.x;
    const int brow = blockIdx.x * 32;
    const int rg   = t >> 6;          // 0..3
    const int col  = (t & 63) * 4;    // 0..252
    const int r0   = rg * 8;

    float acc[8][4];
#pragma unroll
    for (int i = 0; i < 8; ++i)
#pragma unroll
        for (int j = 0; j < 4; ++j) acc[i][j] = 0.f;

    const int ar = t >> 3;            // 0..31 (A-tile row)
    const int ak = (t & 7) * 4;       // 0..28 (A-tile k)

    for (int k0 = 0; k0 < K; k0 += 32) {
        // stage A tile (transposed into LDS)
        float4 a4 = make_float4(0.f, 0.f, 0.f, 0.f);
        if (brow + ar < M)
            a4 = *(const float4*)(A + (size_t)(brow + ar) * K + k0 + ak);
        As[ak + 0][ar] = a4.x;
        As[ak + 1][ar] = a4.y;
        As[ak + 2][ar] = a4.z;
        As[ak + 3][ar] = a4.w;
        // stage W tile: 32x256 floats = 2048 float4, 8 per thread, coalesced
#pragma unroll
        for (int f = 0; f < 8; ++f) {
            int idx4 = t + f * 256;
            int kk = idx4 >> 6;
            int c  = (idx4 & 63) * 4;
            *(float4*)&Ws[kk][c] = *(const float4*)(W + (size_t)(k0 + kk) * DH + c);
        }
        __syncthreads();

#pragma unroll
        for (int kk = 0; kk < 32; ++kk) {
            float4 w4 = *(const float4*)&Ws[kk][col];
            float4 a0 = *(const float4*)&As[kk][r0];
            float4 a1 = *(const float4*)&As[kk][r0 + 4];
            float ar8[8] = {a0.x, a0.y, a0.z, a0.w, a1.x, a1.y, a1.z, a1.w};
#pragma unroll
            for (int i = 0; i < 8; ++i) {
                acc[i][0] += ar8[i] * w4.x;
                acc[i][1] += ar8[i] * w4.y;
                acc[i][2] += ar8[i] * w4.z;
                acc[i][3] += ar8[i] * w4.w;
            }
        }
        __syncthreads();
    }

    float4 b4 = *(const float4*)(bias + col);
#pragma unroll
    for (int i = 0; i < 8; ++i) {
        int row = brow + r0 + i;
        if (row >= M) break;
        float4 o;
        o.x = acc[i][0] + b4.x;
        o.y = acc[i][1] + b4.y;
        o.z = acc[i][2] + b4.z;
        o.w = acc[i][3] + b4.w;
        if (RELU) {
            o.x = fmaxf(o.x, 0.f); o.y = fmaxf(o.y, 0.f);
            o.z = fmaxf(o.z, 0.f); o.w = fmaxf(o.w, 0.f);
        }
        *(float4*)(C + (size_t)row * DH + col) = o;
    }
}

// ------------------------------------------------------------------ launch
static inline size_t align256(size_t x) { return (x + 255) & ~(size_t)255; }

extern "C" void kernel_launch(void* const* d_in, const int* in_sizes, int n_in,
                              void* d_out, int out_size, void* d_ws, size_t ws_size,
                              hipStream_t stream) {
    const float* x   = (const float*)d_in[0];
    const int*   ei  = (const int*)d_in[1];
    const float* w11 = (const float*)d_in[2];
    const float* b11 = (const float*)d_in[3];
    const float* w12 = (const float*)d_in[4];
    const float* b12 = (const float*)d_in[5];
    const float* w21 = (const float*)d_in[6];
    const float* b21 = (const float*)d_in[7];
    const float* w22 = (const float*)d_in[8];
    const float* b22 = (const float*)d_in[9];
    const float* w31 = (const float*)d_in[10];
    const float* b31 = (const float*)d_in[11];
    const float* w32 = (const float*)d_in[12];
    const float* b32 = (const float*)d_in[13];

    const int N = in_sizes[0] / DIN;   // 100000
    const int E = in_sizes[1] / 2;     // 3200000
    const int* src = ei;
    const int* dst = ei + E;

    char* ws = (char*)d_ws;
    float* A = (float*)ws; ws += align256((size_t)N * DH * 4);
    float* B = (float*)ws; ws += align256((size_t)N * DH * 4);
    int* cnt  = (int*)ws;  ws += align256((size_t)N * 4);
    int* rp   = (int*)ws;  ws += align256((size_t)(N + 1) * 4);
    int* cur  = (int*)ws;  ws += align256((size_t)N * 4);
    int* bsum = (int*)ws;  ws += 512;
    int* boff = (int*)ws;  ws += 512;
    int* csr  = (int*)ws;  ws += align256((size_t)E * 4);
    float* O  = (float*)d_out;

    // --- CSR build (same work every call; ws re-poisoned by harness) ---
    k_zero<<<(N + 255) / 256, 256, 0, stream>>>(cnt, N);
    k_hist<<<(E + 255) / 256, 256, 0, stream>>>(dst, cnt, E);
    const int nb = (N + 1023) / 1024;
    k_scan1<<<nb, 1024, 0, stream>>>(cnt, rp, bsum, N);
    k_scan2<<<1, 64, 0, stream>>>(bsum, boff, nb);
    k_scan3<<<nb, 1024, 0, stream>>>(rp, cur, boff, N, E);
    k_scatter<<<(E + 255) / 256, 256, 0, stream>>>(src, dst, cur, csr, E);

    const int gAgg  = (N + 3) / 4;        // one wave per node, 4 waves/block
    const int gGemm = (N + 31) / 32;

    // --- layer 1 ---
    k_agg128<<<gAgg, 256, 0, stream>>>(x, rp, csr, A, N);
    k_gemm<DIN, true ><<<gGemm, 256, 0, stream>>>(A, w11, b11, B, N);
    k_gemm<DH,  true ><<<gGemm, 256, 0, stream>>>(B, w12, b12, A, N);  // h1 = A
    // --- layer 2 ---
    k_agg256<<<gAgg, 256, 0, stream>>>(A, rp, csr, B, N);
    k_gemm<DH,  true ><<<gGemm, 256, 0, stream>>>(B, w21, b21, O, N);  // O as scratch
    k_gemm<DH,  true ><<<gGemm, 256, 0, stream>>>(O, w22, b22, B, N);  // h2 = B
    // --- layer 3 ---
    k_agg256<<<gAgg, 256, 0, stream>>>(B, rp, csr, A, N);
    k_gemm<DH,  true ><<<gGemm, 256, 0, stream>>>(A, w31, b31, B, N);
    k_gemm<DH,  false><<<gGemm, 256, 0, stream>>>(B, w32, b32, O, N);  // final
}

// Round 2
// 1550.954 us; speedup vs baseline: 1.6822x; 1.6822x over previous
//
#include <hip/hip_runtime.h>
#include <hip/hip_bf16.h>
#include <hip/hip_fp16.h>

// GIN 3-layer forward, MI355X (gfx950).
// R2: fp16 feature planes (halve gather bytes) + MFMA fp16 GEMM with
// error-compensated weights (W = Whi + Wlo fp16 planes, 2 MFMA products,
// fp32 accumulate). A-operand single fp16 (only precision loss, ~6e-4 rel).

#define DIN 128
#define DH  256
#define BM  256
#define BN  128
#define BK  64

// ---------------------------------------------------------------- CSR build
__global__ __launch_bounds__(256) void k_zero(int* p, int n) {
    int i = blockIdx.x * 256 + threadIdx.x;
    if (i < n) p[i] = 0;
}

__global__ __launch_bounds__(256) void k_hist(const int* __restrict__ dst,
                                              int* __restrict__ cnt, int E) {
    int e = blockIdx.x * 256 + threadIdx.x;
    if (e < E) atomicAdd(&cnt[dst[e]], 1);
}

__global__ __launch_bounds__(1024) void k_scan1(const int* __restrict__ cnt,
                                                int* __restrict__ rp,
                                                int* __restrict__ bsum, int n) {
    __shared__ int tmp[1024];
    int tid = threadIdx.x;
    int gid = blockIdx.x * 1024 + tid;
    int v = (gid < n) ? cnt[gid] : 0;
    tmp[tid] = v;
    __syncthreads();
    for (int off = 1; off < 1024; off <<= 1) {
        int add = (tid >= off) ? tmp[tid - off] : 0;
        __syncthreads();
        tmp[tid] += add;
        __syncthreads();
    }
    if (gid < n) rp[gid] = tmp[tid] - v;
    if (tid == 1023) bsum[blockIdx.x] = tmp[tid];
}

__global__ void k_scan2(const int* __restrict__ bsum, int* __restrict__ boff, int nb) {
    if (threadIdx.x == 0 && blockIdx.x == 0) {
        int s = 0;
        for (int i = 0; i < nb; ++i) { boff[i] = s; s += bsum[i]; }
    }
}

__global__ __launch_bounds__(1024) void k_scan3(int* __restrict__ rp,
                                                int* __restrict__ cur,
                                                const int* __restrict__ boff,
                                                int n, int E) {
    int gid = blockIdx.x * 1024 + threadIdx.x;
    if (gid < n) {
        int v = rp[gid] + boff[blockIdx.x];
        rp[gid]  = v;
        cur[gid] = v;
    }
    if (gid == 0) rp[n] = E;
}

__global__ __launch_bounds__(256) void k_scatter(const int* __restrict__ src,
                                                 const int* __restrict__ dst,
                                                 int* __restrict__ cur,
                                                 int* __restrict__ csr, int E) {
    int e = blockIdx.x * 256 + threadIdx.x;
    if (e < E) {
        int pos = atomicAdd(&cur[dst[e]], 1);
        csr[pos] = src[e];
    }
}

// ---------------------------------------------------------- weight pre-split
// W[K x 256] fp32 -> Wt_hi/Wt_lo [256 x K] fp16 (transposed, error-compensated)
__global__ __launch_bounds__(256) void k_wsplit(const float* __restrict__ W,
                                                __half* __restrict__ hi,
                                                __half* __restrict__ lo, int K) {
    int idx = blockIdx.x * 256 + threadIdx.x;
    if (idx >= K * 256) return;
    int k = idx >> 8, c = idx & 255;
    float v = W[idx];
    __half h = __float2half(v);
    float r = v - __half2float(h);
    hi[c * K + k] = h;
    lo[c * K + k] = __float2half(r);
}

// ------------------------------------------------------------- aggregation
__device__ __forceinline__ void addrow4(unsigned lo, unsigned hi,
                                        float& a0, float& a1, float& a2, float& a3) {
    __half2 h0 = __builtin_bit_cast(__half2, lo);
    __half2 h1 = __builtin_bit_cast(__half2, hi);
    float2 f0 = __half22float2(h0);
    float2 f1 = __half22float2(h1);
    a0 += f0.x; a1 += f0.y; a2 += f1.x; a3 += f1.y;
}

// out[i] = h[i] + sum_{j->i} h[j]; H fp16 [Mpad x 256]; one wave per node.
__global__ __launch_bounds__(256) void k_aggh256(const __half* __restrict__ H,
                                                 const int* __restrict__ rp,
                                                 const int* __restrict__ csr,
                                                 __half* __restrict__ out, int n) {
    int node = (int)((blockIdx.x * 256 + threadIdx.x) >> 6);
    if (node >= n) return;
    int lane = threadIdx.x & 63;
    const size_t lo4 = (size_t)lane * 4;                   // 4 fp16 per lane
    float a0, a1, a2, a3;
    {
        uint2 v = *(const uint2*)(H + (size_t)node * DH + lo4);
        a0 = a1 = a2 = a3 = 0.f;
        addrow4(v.x, v.y, a0, a1, a2, a3);                 // self (eps=0)
    }
    int p = rp[node], pe = rp[node + 1];
    for (; p + 3 < pe; p += 4) {
        int j0 = csr[p], j1 = csr[p + 1], j2 = csr[p + 2], j3 = csr[p + 3];
        uint2 v0 = *(const uint2*)(H + (size_t)j0 * DH + lo4);
        uint2 v1 = *(const uint2*)(H + (size_t)j1 * DH + lo4);
        uint2 v2 = *(const uint2*)(H + (size_t)j2 * DH + lo4);
        uint2 v3 = *(const uint2*)(H + (size_t)j3 * DH + lo4);
        addrow4(v0.x, v0.y, a0, a1, a2, a3);
        addrow4(v1.x, v1.y, a0, a1, a2, a3);
        addrow4(v2.x, v2.y, a0, a1, a2, a3);
        addrow4(v3.x, v3.y, a0, a1, a2, a3);
    }
    for (; p < pe; ++p) {
        uint2 v = *(const uint2*)(H + (size_t)csr[p] * DH + lo4);
        addrow4(v.x, v.y, a0, a1, a2, a3);
    }
    __half2 o0 = __floats2half2_rn(a0, a1);
    __half2 o1 = __floats2half2_rn(a2, a3);
    uint2 ov;
    ov.x = __builtin_bit_cast(unsigned, o0);
    ov.y = __builtin_bit_cast(unsigned, o1);
    *(uint2*)(out + (size_t)node * DH + lo4) = ov;
}

// layer 1: gather fp32 x [N x 128], write fp16 A1 [Mpad x 128]
__global__ __launch_bounds__(256) void k_agg128f(const float* __restrict__ X,
                                                 const int* __restrict__ rp,
                                                 const int* __restrict__ csr,
                                                 __half* __restrict__ out, int n) {
    int node = (int)((blockIdx.x * 256 + threadIdx.x) >> 6);
    if (node >= n) return;
    int lane = threadIdx.x & 63;
    const size_t lo2 = (size_t)lane * 2;                   // 2 fp32 per lane
    float2 acc = *(const float2*)(X + (size_t)node * DIN + lo2);
    int p = rp[node], pe = rp[node + 1];
    for (; p + 3 < pe; p += 4) {
        int j0 = csr[p], j1 = csr[p + 1], j2 = csr[p + 2], j3 = csr[p + 3];
        float2 v0 = *(const float2*)(X + (size_t)j0 * DIN + lo2);
        float2 v1 = *(const float2*)(X + (size_t)j1 * DIN + lo2);
        float2 v2 = *(const float2*)(X + (size_t)j2 * DIN + lo2);
        float2 v3 = *(const float2*)(X + (size_t)j3 * DIN + lo2);
        acc.x += v0.x + v1.x + v2.x + v3.x;
        acc.y += v0.y + v1.y + v2.y + v3.y;
    }
    for (; p < pe; ++p) {
        float2 v = *(const float2*)(X + (size_t)csr[p] * DIN + lo2);
        acc.x += v.x; acc.y += v.y;
    }
    __half2 o = __floats2half2_rn(acc.x, acc.y);
    *(unsigned*)(out + (size_t)node * DIN + lo2) = __builtin_bit_cast(unsigned, o);
}

// ------------------------------------------------------------------- GEMM
// C[M x 256] = A[M x K](fp16) @ (Whi+Wlo)[K x 256] + bias; fp32 accumulate.
// BM=256 BN=128 BK=64, 4 waves, wave-tile 128x64 (8x4 frags of 16x16x32).
// LDS XOR swizzle: 16B chunk q of row r stored at slot q^(r&7) -> conflict-free
// ds_read_b128 fragment reads (G4). MODE 0: fp16+relu out; MODE 1: fp32 out.
typedef __attribute__((ext_vector_type(8))) _Float16 f16x8;
typedef __attribute__((ext_vector_type(4))) float     f32x4;

template<int K, int MODE>
__global__ __launch_bounds__(256, 2) void k_gemm_mfma(
        const __half* __restrict__ A,     // [Mpad x K]
        const __half* __restrict__ Wthi,  // [256 x K] (transposed W)
        const __half* __restrict__ Wtlo,  // [256 x K]
        const float* __restrict__ bias,   // [256]
        void* __restrict__ Cout, int M) {
    __shared__ __align__(16) __half As[BM * BK];   // 32 KB
    __shared__ __align__(16) __half Whs[BN * BK];  // 16 KB
    __shared__ __align__(16) __half Wls[BN * BK];  // 16 KB

    const int t    = threadIdx.x;
    const int lane = t & 63;
    const int wid  = t >> 6;          // 0..3
    const int wr   = wid >> 1;        // 0..1 (row block of 128)
    const int wc   = wid & 1;         // 0..1 (col block of 64)
    const int brow = (int)blockIdx.x * BM;
    const int bcol = (int)blockIdx.y * BN;

    f32x4 acc[8][4] = {};

    for (int k0 = 0; k0 < K; k0 += BK) {
        // stage A tile: 256 rows x 8 chunks(16B) = 2048 chunks, 8/thread
#pragma unroll
        for (int i = 0; i < 8; ++i) {
            int idx = i * 256 + t;
            int r = idx >> 3, q = idx & 7;
            uint4 v = *(const uint4*)(A + (size_t)(brow + r) * K + k0 + q * 8);
            *(uint4*)((char*)As + r * 128 + ((q ^ (r & 7)) << 4)) = v;
        }
        // stage W tiles: 128 rows x 8 chunks per plane, 4/thread/plane
#pragma unroll
        for (int i = 0; i < 4; ++i) {
            int idx = i * 256 + t;
            int c = idx >> 3, q = idx & 7;
            size_t go = (size_t)(bcol + c) * K + k0 + q * 8;
            uint4 vh = *(const uint4*)(Wthi + go);
            uint4 vl = *(const uint4*)(Wtlo + go);
            int off = c * 128 + ((q ^ (c & 7)) << 4);
            *(uint4*)((char*)Whs + off) = vh;
            *(uint4*)((char*)Wls + off) = vl;
        }
        __syncthreads();

#pragma unroll
        for (int kk = 0; kk < 2; ++kk) {
            const int qa = kk * 4 + (lane >> 4);
            f16x8 af[8], wh[4], wl[4];
#pragma unroll
            for (int mi = 0; mi < 8; ++mi) {
                int r = wr * 128 + mi * 16 + (lane & 15);
                af[mi] = *(const f16x8*)((const char*)As + r * 128 + ((qa ^ (r & 7)) << 4));
            }
#pragma unroll
            for (int ni = 0; ni < 4; ++ni) {
                int c = wc * 64 + ni * 16 + (lane & 15);
                int off = c * 128 + ((qa ^ (c & 7)) << 4);
                wh[ni] = *(const f16x8*)((const char*)Whs + off);
                wl[ni] = *(const f16x8*)((const char*)Wls + off);
            }
#pragma unroll
            for (int mi = 0; mi < 8; ++mi)
#pragma unroll
                for (int ni = 0; ni < 4; ++ni) {
                    acc[mi][ni] = __builtin_amdgcn_mfma_f32_16x16x32_f16(af[mi], wh[ni], acc[mi][ni], 0, 0, 0);
                    acc[mi][ni] = __builtin_amdgcn_mfma_f32_16x16x32_f16(af[mi], wl[ni], acc[mi][ni], 0, 0, 0);
                }
        }
        __syncthreads();
    }

    // epilogue: C/D layout col = lane&15, row = (lane>>4)*4 + reg
#pragma unroll
    for (int ni = 0; ni < 4; ++ni) {
        const int c = bcol + wc * 64 + ni * 16 + (lane & 15);
        const float bz = bias[c];
#pragma unroll
        for (int mi = 0; mi < 8; ++mi) {
            const int r0 = brow + wr * 128 + mi * 16 + ((lane >> 4) << 2);
#pragma unroll
            for (int j = 0; j < 4; ++j) {
                int row = r0 + j;
                if (row < M) {
                    float v = acc[mi][ni][j] + bz;
                    if (MODE == 0) {
                        v = fmaxf(v, 0.f);
                        ((__half*)Cout)[(size_t)row * DH + c] = __float2half(v);
                    } else {
                        ((float*)Cout)[(size_t)row * DH + c] = v;
                    }
                }
            }
        }
    }
}

// ------------------------------------------------------------------ launch
static inline size_t align256(size_t x) { return (x + 255) & ~(size_t)255; }

extern "C" void kernel_launch(void* const* d_in, const int* in_sizes, int n_in,
                              void* d_out, int out_size, void* d_ws, size_t ws_size,
                              hipStream_t stream) {
    const float* x   = (const float*)d_in[0];
    const int*   ei  = (const int*)d_in[1];
    const float* W[6]  = {(const float*)d_in[2], (const float*)d_in[4],
                          (const float*)d_in[6], (const float*)d_in[8],
                          (const float*)d_in[10], (const float*)d_in[12]};
    const float* Bv[6] = {(const float*)d_in[3], (const float*)d_in[5],
                          (const float*)d_in[7], (const float*)d_in[9],
                          (const float*)d_in[11], (const float*)d_in[13]};

    const int N = in_sizes[0] / DIN;            // 100000
    const int E = in_sizes[1] / 2;              // 3200000
    const int Mpad = ((N + BM - 1) / BM) * BM;  // 100096
    const int* src = ei;
    const int* dst = ei + E;

    char* ws = (char*)d_ws;
    __half* A1 = (__half*)ws; ws += align256((size_t)Mpad * DIN * 2);  // 25.6 MB
    __half* Ah = (__half*)ws; ws += align256((size_t)Mpad * DH * 2);   // 51.2 MB
    __half* T  = (__half*)ws; ws += align256((size_t)Mpad * DH * 2);
    __half* Hh = (__half*)ws; ws += align256((size_t)Mpad * DH * 2);
    __half* Wh[6]; __half* Wl[6];
    const int Ks[6] = {DIN, DH, DH, DH, DH, DH};
    for (int i = 0; i < 6; ++i) {
        Wh[i] = (__half*)ws; ws += align256((size_t)Ks[i] * DH * 2);
        Wl[i] = (__half*)ws; ws += align256((size_t)Ks[i] * DH * 2);
    }
    int* cnt  = (int*)ws;  ws += align256((size_t)N * 4);
    int* rp   = (int*)ws;  ws += align256((size_t)(N + 1) * 4);
    int* cur  = (int*)ws;  ws += align256((size_t)N * 4);
    int* bsum = (int*)ws;  ws += 512;
    int* boff = (int*)ws;  ws += 512;
    int* csr  = (int*)ws;  ws += align256((size_t)E * 4);
    float* O  = (float*)d_out;

    // --- CSR build ---
    k_zero<<<(N + 255) / 256, 256, 0, stream>>>(cnt, N);
    k_hist<<<(E + 255) / 256, 256, 0, stream>>>(dst, cnt, E);
    const int nb = (N + 1023) / 1024;
    k_scan1<<<nb, 1024, 0, stream>>>(cnt, rp, bsum, N);
    k_scan2<<<1, 64, 0, stream>>>(bsum, boff, nb);
    k_scan3<<<nb, 1024, 0, stream>>>(rp, cur, boff, N, E);
    k_scatter<<<(E + 255) / 256, 256, 0, stream>>>(src, dst, cur, csr, E);

    // --- weight pre-split (transposed, hi+lo fp16) ---
    for (int i = 0; i < 6; ++i)
        k_wsplit<<<(Ks[i] * 256 + 255) / 256, 256, 0, stream>>>(W[i], Wh[i], Wl[i], Ks[i]);

    const int gAgg = (N + 3) / 4;
    dim3 gGemm(Mpad / BM, DH / BN);   // (391, 2)

    // --- layer 1 ---
    k_agg128f<<<gAgg, 256, 0, stream>>>(x, rp, csr, A1, N);
    k_gemm_mfma<DIN, 0><<<gGemm, 256, 0, stream>>>(A1, Wh[0], Wl[0], Bv[0], T, N);
    k_gemm_mfma<DH,  0><<<gGemm, 256, 0, stream>>>(T,  Wh[1], Wl[1], Bv[1], Hh, N);
    // --- layer 2 ---
    k_aggh256<<<gAgg, 256, 0, stream>>>(Hh, rp, csr, Ah, N);
    k_gemm_mfma<DH,  0><<<gGemm, 256, 0, stream>>>(Ah, Wh[2], Wl[2], Bv[2], T, N);
    k_gemm_mfma<DH,  0><<<gGemm, 256, 0, stream>>>(T,  Wh[3], Wl[3], Bv[3], Hh, N);
    // --- layer 3 ---
    k_aggh256<<<gAgg, 256, 0, stream>>>(Hh, rp, csr, Ah, N);
    k_gemm_mfma<DH,  0><<<gGemm, 256, 0, stream>>>(Ah, Wh[4], Wl[4], Bv[4], T, N);
    k_gemm_mfma<DH,  1><<<gGemm, 256, 0, stream>>>(T,  Wh[5], Wl[5], Bv[5], O, N);
}

// Round 3
// 1207.792 us; speedup vs baseline: 2.1601x; 1.2841x over previous
//
#include <hip/hip_runtime.h>
#include <hip/hip_bf16.h>
#include <hip/hip_fp16.h>

// GIN 3-layer forward, MI355X (gfx950).
// R3: CSR build via two-level counting sort (zero global atomics; LDS-local
// scatter windows) replacing atomic hist+scatter (~350us -> ~50us predicted).
// Layer-1 gather from fp16 x-table. MFMA GEMM (hi+lo fp16 weights) unchanged.

#define DIN 128
#define DH  256
#define BM  256
#define BN  128
#define BK  64

#define BSHIFT 9
#define BNODES 512          // nodes per bucket = 1<<BSHIFT
#define MAXB   256          // max buckets (N <= 131072)
#define PBLK   256          // partition blocks

// ------------------------------------------------- CSR build (counting sort)
// Phase A: per-block histogram over buckets (LDS, no global atomics).
__global__ __launch_bounds__(1024) void k_bhist(const int* __restrict__ dst,
                                                int* __restrict__ cntMat,
                                                int E, int nbuck, int chunk) {
    __shared__ int h[MAXB];
    for (int i = threadIdx.x; i < nbuck; i += 1024) h[i] = 0;
    __syncthreads();
    const int b = blockIdx.x;
    const int lo = b * chunk, hi = min(lo + chunk, E);
    for (int i = lo + (int)threadIdx.x; i < hi; i += 1024)
        atomicAdd(&h[dst[i] >> BSHIFT], 1);
    __syncthreads();
    for (int i = threadIdx.x; i < nbuck; i += 1024) cntMat[b * nbuck + i] = h[i];
}

// Phase B: bucket totals -> bucket bases; per-(block,bucket) write bases.
__global__ __launch_bounds__(256) void k_bscan(const int* __restrict__ cntMat,
                                               int* __restrict__ bbase,
                                               int* __restrict__ baseMat,
                                               int nbuck, int E) {
    __shared__ int tot[MAXB];
    __shared__ int base[MAXB + 1];
    const int k = threadIdx.x;
    if (k < nbuck) {
        int s = 0;
        for (int b = 0; b < PBLK; ++b) s += cntMat[b * nbuck + k];
        tot[k] = s;
    }
    __syncthreads();
    if (k == 0) {
        int acc = 0;
        for (int i = 0; i < nbuck; ++i) { base[i] = acc; acc += tot[i]; }
        base[nbuck] = acc;
    }
    __syncthreads();
    if (k < nbuck) {
        bbase[k] = base[k];
        int acc = base[k];
        for (int b = 0; b < PBLK; ++b) { baseMat[b * nbuck + k] = acc; acc += cntMat[b * nbuck + k]; }
    }
    if (k == 0) bbase[nbuck] = E;
}

// Phase C: deterministic partition of (dst,src) pairs into bucket regions.
__global__ __launch_bounds__(1024) void k_bpart(const int* __restrict__ src,
                                                const int* __restrict__ dst,
                                                const int* __restrict__ baseMat,
                                                uint2* __restrict__ pairb,
                                                int E, int nbuck, int chunk) {
    __shared__ int cur[MAXB];
    const int b = blockIdx.x;
    for (int i = threadIdx.x; i < nbuck; i += 1024) cur[i] = baseMat[b * nbuck + i];
    __syncthreads();
    const int lo = b * chunk, hi = min(lo + chunk, E);
    for (int i = lo + (int)threadIdx.x; i < hi; i += 1024) {
        int d = dst[i], s = src[i];
        int pos = atomicAdd(&cur[d >> BSHIFT], 1);   // LDS atomic only
        pairb[pos] = make_uint2((unsigned)d, (unsigned)s);
    }
}

// Phase D: per-bucket CSR finalize — hist, scan, scatter all bucket-local.
__global__ __launch_bounds__(1024) void k_bcsr(const uint2* __restrict__ pairb,
                                               const int* __restrict__ bbase,
                                               int* __restrict__ rp,
                                               int* __restrict__ csr,
                                               int N, int E) {
    __shared__ int cnt[BNODES];
    __shared__ int cur[BNODES];
    const int k = blockIdx.x;
    const int node0 = k << BSHIFT;
    const int nn = min(BNODES, N - node0);
    const int lo = bbase[k], hi = bbase[k + 1];
    const int tid = threadIdx.x;

    for (int i = tid; i < BNODES; i += 1024) cnt[i] = 0;
    __syncthreads();
    for (int i = lo + tid; i < hi; i += 1024)
        atomicAdd(&cnt[pairb[i].x - node0], 1);
    __syncthreads();

    int v = 0;
    if (tid < BNODES) { v = cnt[tid]; cur[tid] = v; }
    __syncthreads();
    for (int off = 1; off < BNODES; off <<= 1) {
        int add = (tid < BNODES && tid >= off) ? cur[tid - off] : 0;
        __syncthreads();
        if (tid < BNODES) cur[tid] += add;
        __syncthreads();
    }
    if (tid < nn) {
        int start = lo + cur[tid] - v;    // exclusive scan -> absolute position
        rp[node0 + tid] = start;
        cur[tid] = start;
    }
    __syncthreads();
    for (int i = lo + tid; i < hi; i += 1024) {
        uint2 e = pairb[i];
        int pos = atomicAdd(&cur[e.x - node0], 1);   // LDS atomic
        csr[pos] = (int)e.y;                          // write within 64KB window
    }
    if (k == 0 && tid == 0) rp[N] = E;
}

// ---------------------------------------------------------- weight pre-split
__global__ __launch_bounds__(256) void k_wsplit(const float* __restrict__ W,
                                                __half* __restrict__ hi,
                                                __half* __restrict__ lo, int K) {
    int idx = blockIdx.x * 256 + threadIdx.x;
    if (idx >= K * 256) return;
    int k = idx >> 8, c = idx & 255;
    float v = W[idx];
    __half h = __float2half(v);
    float r = v - __half2float(h);
    hi[c * K + k] = h;
    lo[c * K + k] = __float2half(r);
}

// ------------------------------------------------------------- x -> fp16
__global__ __launch_bounds__(256) void k_castx(const float* __restrict__ X,
                                               __half* __restrict__ Xh, int n4) {
    int i = blockIdx.x * 256 + threadIdx.x;
    if (i >= n4) return;
    float4 f = *(const float4*)(X + (size_t)i * 4);
    __half2 h0 = __floats2half2_rn(f.x, f.y);
    __half2 h1 = __floats2half2_rn(f.z, f.w);
    uint2 o;
    o.x = __builtin_bit_cast(unsigned, h0);
    o.y = __builtin_bit_cast(unsigned, h1);
    *(uint2*)(Xh + (size_t)i * 4) = o;
}

// ------------------------------------------------------------- aggregation
__device__ __forceinline__ void addrow4(unsigned lo, unsigned hi,
                                        float& a0, float& a1, float& a2, float& a3) {
    __half2 h0 = __builtin_bit_cast(__half2, lo);
    __half2 h1 = __builtin_bit_cast(__half2, hi);
    float2 f0 = __half22float2(h0);
    float2 f1 = __half22float2(h1);
    a0 += f0.x; a1 += f0.y; a2 += f1.x; a3 += f1.y;
}

// out[i] = h[i] + sum_{j->i} h[j]; H fp16 [Mpad x 256]; one wave per node.
__global__ __launch_bounds__(256) void k_aggh256(const __half* __restrict__ H,
                                                 const int* __restrict__ rp,
                                                 const int* __restrict__ csr,
                                                 __half* __restrict__ out, int n) {
    int node = (int)((blockIdx.x * 256 + threadIdx.x) >> 6);
    if (node >= n) return;
    int lane = threadIdx.x & 63;
    const size_t lo4 = (size_t)lane * 4;
    float a0, a1, a2, a3;
    {
        uint2 v = *(const uint2*)(H + (size_t)node * DH + lo4);
        a0 = a1 = a2 = a3 = 0.f;
        addrow4(v.x, v.y, a0, a1, a2, a3);
    }
    int p = rp[node], pe = rp[node + 1];
    for (; p + 3 < pe; p += 4) {
        int j0 = csr[p], j1 = csr[p + 1], j2 = csr[p + 2], j3 = csr[p + 3];
        uint2 v0 = *(const uint2*)(H + (size_t)j0 * DH + lo4);
        uint2 v1 = *(const uint2*)(H + (size_t)j1 * DH + lo4);
        uint2 v2 = *(const uint2*)(H + (size_t)j2 * DH + lo4);
        uint2 v3 = *(const uint2*)(H + (size_t)j3 * DH + lo4);
        addrow4(v0.x, v0.y, a0, a1, a2, a3);
        addrow4(v1.x, v1.y, a0, a1, a2, a3);
        addrow4(v2.x, v2.y, a0, a1, a2, a3);
        addrow4(v3.x, v3.y, a0, a1, a2, a3);
    }
    for (; p < pe; ++p) {
        uint2 v = *(const uint2*)(H + (size_t)csr[p] * DH + lo4);
        addrow4(v.x, v.y, a0, a1, a2, a3);
    }
    __half2 o0 = __floats2half2_rn(a0, a1);
    __half2 o1 = __floats2half2_rn(a2, a3);
    uint2 ov;
    ov.x = __builtin_bit_cast(unsigned, o0);
    ov.y = __builtin_bit_cast(unsigned, o1);
    *(uint2*)(out + (size_t)node * DH + lo4) = ov;
}

// layer-1: gather fp16 x-table [N x 128]; one wave per node, 4B/lane.
__global__ __launch_bounds__(256) void k_aggh128(const __half* __restrict__ H,
                                                 const int* __restrict__ rp,
                                                 const int* __restrict__ csr,
                                                 __half* __restrict__ out, int n) {
    int node = (int)((blockIdx.x * 256 + threadIdx.x) >> 6);
    if (node >= n) return;
    int lane = threadIdx.x & 63;
    const size_t lo2 = (size_t)lane * 2;
    float a0, a1;
    {
        unsigned v = *(const unsigned*)(H + (size_t)node * DIN + lo2);
        float2 f = __half22float2(__builtin_bit_cast(__half2, v));
        a0 = f.x; a1 = f.y;
    }
    int p = rp[node], pe = rp[node + 1];
    for (; p + 3 < pe; p += 4) {
        int j0 = csr[p], j1 = csr[p + 1], j2 = csr[p + 2], j3 = csr[p + 3];
        unsigned v0 = *(const unsigned*)(H + (size_t)j0 * DIN + lo2);
        unsigned v1 = *(const unsigned*)(H + (size_t)j1 * DIN + lo2);
        unsigned v2 = *(const unsigned*)(H + (size_t)j2 * DIN + lo2);
        unsigned v3 = *(const unsigned*)(H + (size_t)j3 * DIN + lo2);
        float2 f0 = __half22float2(__builtin_bit_cast(__half2, v0));
        float2 f1 = __half22float2(__builtin_bit_cast(__half2, v1));
        float2 f2 = __half22float2(__builtin_bit_cast(__half2, v2));
        float2 f3 = __half22float2(__builtin_bit_cast(__half2, v3));
        a0 += f0.x + f1.x + f2.x + f3.x;
        a1 += f0.y + f1.y + f2.y + f3.y;
    }
    for (; p < pe; ++p) {
        unsigned v = *(const unsigned*)(H + (size_t)csr[p] * DIN + lo2);
        float2 f = __half22float2(__builtin_bit_cast(__half2, v));
        a0 += f.x; a1 += f.y;
    }
    __half2 o = __floats2half2_rn(a0, a1);
    *(unsigned*)(out + (size_t)node * DIN + lo2) = __builtin_bit_cast(unsigned, o);
}

// ------------------------------------------------------------------- GEMM
typedef __attribute__((ext_vector_type(8))) _Float16 f16x8;
typedef __attribute__((ext_vector_type(4))) float     f32x4;

template<int K, int MODE>
__global__ __launch_bounds__(256, 2) void k_gemm_mfma(
        const __half* __restrict__ A,     // [Mpad x K]
        const __half* __restrict__ Wthi,  // [256 x K]
        const __half* __restrict__ Wtlo,  // [256 x K]
        const float* __restrict__ bias,
        void* __restrict__ Cout, int M) {
    __shared__ __align__(16) __half As[BM * BK];
    __shared__ __align__(16) __half Whs[BN * BK];
    __shared__ __align__(16) __half Wls[BN * BK];

    const int t    = threadIdx.x;
    const int lane = t & 63;
    const int wid  = t >> 6;
    const int wr   = wid >> 1;
    const int wc   = wid & 1;
    const int brow = (int)blockIdx.x * BM;
    const int bcol = (int)blockIdx.y * BN;

    f32x4 acc[8][4] = {};

    for (int k0 = 0; k0 < K; k0 += BK) {
#pragma unroll
        for (int i = 0; i < 8; ++i) {
            int idx = i * 256 + t;
            int r = idx >> 3, q = idx & 7;
            uint4 v = *(const uint4*)(A + (size_t)(brow + r) * K + k0 + q * 8);
            *(uint4*)((char*)As + r * 128 + ((q ^ (r & 7)) << 4)) = v;
        }
#pragma unroll
        for (int i = 0; i < 4; ++i) {
            int idx = i * 256 + t;
            int c = idx >> 3, q = idx & 7;
            size_t go = (size_t)(bcol + c) * K + k0 + q * 8;
            uint4 vh = *(const uint4*)(Wthi + go);
            uint4 vl = *(const uint4*)(Wtlo + go);
            int off = c * 128 + ((q ^ (c & 7)) << 4);
            *(uint4*)((char*)Whs + off) = vh;
            *(uint4*)((char*)Wls + off) = vl;
        }
        __syncthreads();

#pragma unroll
        for (int kk = 0; kk < 2; ++kk) {
            const int qa = kk * 4 + (lane >> 4);
            f16x8 af[8], wh[4], wl[4];
#pragma unroll
            for (int mi = 0; mi < 8; ++mi) {
                int r = wr * 128 + mi * 16 + (lane & 15);
                af[mi] = *(const f16x8*)((const char*)As + r * 128 + ((qa ^ (r & 7)) << 4));
            }
#pragma unroll
            for (int ni = 0; ni < 4; ++ni) {
                int c = wc * 64 + ni * 16 + (lane & 15);
                int off = c * 128 + ((qa ^ (c & 7)) << 4);
                wh[ni] = *(const f16x8*)((const char*)Whs + off);
                wl[ni] = *(const f16x8*)((const char*)Wls + off);
            }
#pragma unroll
            for (int mi = 0; mi < 8; ++mi)
#pragma unroll
                for (int ni = 0; ni < 4; ++ni) {
                    acc[mi][ni] = __builtin_amdgcn_mfma_f32_16x16x32_f16(af[mi], wh[ni], acc[mi][ni], 0, 0, 0);
                    acc[mi][ni] = __builtin_amdgcn_mfma_f32_16x16x32_f16(af[mi], wl[ni], acc[mi][ni], 0, 0, 0);
                }
        }
        __syncthreads();
    }

#pragma unroll
    for (int ni = 0; ni < 4; ++ni) {
        const int c = bcol + wc * 64 + ni * 16 + (lane & 15);
        const float bz = bias[c];
#pragma unroll
        for (int mi = 0; mi < 8; ++mi) {
            const int r0 = brow + wr * 128 + mi * 16 + ((lane >> 4) << 2);
#pragma unroll
            for (int j = 0; j < 4; ++j) {
                int row = r0 + j;
                if (row < M) {
                    float v = acc[mi][ni][j] + bz;
                    if (MODE == 0) {
                        v = fmaxf(v, 0.f);
                        ((__half*)Cout)[(size_t)row * DH + c] = __float2half(v);
                    } else {
                        ((float*)Cout)[(size_t)row * DH + c] = v;
                    }
                }
            }
        }
    }
}

// ------------------------------------------------------------------ launch
static inline size_t align256(size_t x) { return (x + 255) & ~(size_t)255; }

extern "C" void kernel_launch(void* const* d_in, const int* in_sizes, int n_in,
                              void* d_out, int out_size, void* d_ws, size_t ws_size,
                              hipStream_t stream) {
    const float* x   = (const float*)d_in[0];
    const int*   ei  = (const int*)d_in[1];
    const float* W[6]  = {(const float*)d_in[2], (const float*)d_in[4],
                          (const float*)d_in[6], (const float*)d_in[8],
                          (const float*)d_in[10], (const float*)d_in[12]};
    const float* Bv[6] = {(const float*)d_in[3], (const float*)d_in[5],
                          (const float*)d_in[7], (const float*)d_in[9],
                          (const float*)d_in[11], (const float*)d_in[13]};

    const int N = in_sizes[0] / DIN;
    const int E = in_sizes[1] / 2;
    const int Mpad = ((N + BM - 1) / BM) * BM;
    const int* src = ei;
    const int* dst = ei + E;
    const int nbuck  = (N + BNODES - 1) / BNODES;          // 196
    const int chunkE = (E + PBLK - 1) / PBLK;              // 12500

    char* ws = (char*)d_ws;
    __half* A1 = (__half*)ws; ws += align256((size_t)Mpad * DIN * 2);
    __half* Ah = (__half*)ws; ws += align256((size_t)Mpad * DH * 2);
    __half* T  = (__half*)ws; ws += align256((size_t)Mpad * DH * 2);
    __half* Hh = (__half*)ws; ws += align256((size_t)Mpad * DH * 2);
    __half* Xh = (__half*)T;          // alias: T first written after Xh last read
    uint2* pairb = (uint2*)Ah;        // alias: Ah first written after pairb dead
    __half* Wh[6]; __half* Wl[6];
    const int Ks[6] = {DIN, DH, DH, DH, DH, DH};
    for (int i = 0; i < 6; ++i) {
        Wh[i] = (__half*)ws; ws += align256((size_t)Ks[i] * DH * 2);
        Wl[i] = (__half*)ws; ws += align256((size_t)Ks[i] * DH * 2);
    }
    int* cntMat  = (int*)ws; ws += align256((size_t)PBLK * MAXB * 4);
    int* baseMat = (int*)ws; ws += align256((size_t)PBLK * MAXB * 4);
    int* bbase   = (int*)ws; ws += align256((size_t)(MAXB + 1) * 4);
    int* rp      = (int*)ws; ws += align256((size_t)(N + 1) * 4);
    int* csr     = (int*)ws; ws += align256((size_t)E * 4);
    float* O = (float*)d_out;

    // --- CSR build (counting sort; no global atomics) ---
    k_bhist<<<PBLK, 1024, 0, stream>>>(dst, cntMat, E, nbuck, chunkE);
    k_bscan<<<1, 256, 0, stream>>>(cntMat, bbase, baseMat, nbuck, E);
    k_bpart<<<PBLK, 1024, 0, stream>>>(src, dst, baseMat, pairb, E, nbuck, chunkE);
    k_bcsr<<<nbuck, 1024, 0, stream>>>(pairb, bbase, rp, csr, N, E);

    // --- weights + x cast ---
    for (int i = 0; i < 6; ++i)
        k_wsplit<<<(Ks[i] * 256 + 255) / 256, 256, 0, stream>>>(W[i], Wh[i], Wl[i], Ks[i]);
    k_castx<<<(N * DIN / 4 + 255) / 256, 256, 0, stream>>>(x, Xh, N * DIN / 4);

    const int gAgg = (N + 3) / 4;
    dim3 gGemm(Mpad / BM, DH / BN);

    // --- layer 1 ---
    k_aggh128<<<gAgg, 256, 0, stream>>>(Xh, rp, csr, A1, N);
    k_gemm_mfma<DIN, 0><<<gGemm, 256, 0, stream>>>(A1, Wh[0], Wl[0], Bv[0], T, N);
    k_gemm_mfma<DH,  0><<<gGemm, 256, 0, stream>>>(T,  Wh[1], Wl[1], Bv[1], Hh, N);
    // --- layer 2 ---
    k_aggh256<<<gAgg, 256, 0, stream>>>(Hh, rp, csr, Ah, N);
    k_gemm_mfma<DH,  0><<<gGemm, 256, 0, stream>>>(Ah, Wh[2], Wl[2], Bv[2], T, N);
    k_gemm_mfma<DH,  0><<<gGemm, 256, 0, stream>>>(T,  Wh[3], Wl[3], Bv[3], Hh, N);
    // --- layer 3 ---
    k_aggh256<<<gAgg, 256, 0, stream>>>(Hh, rp, csr, Ah, N);
    k_gemm_mfma<DH,  0><<<gGemm, 256, 0, stream>>>(Ah, Wh[4], Wl[4], Bv[4], T, N);
    k_gemm_mfma<DH,  1><<<gGemm, 256, 0, stream>>>(T,  Wh[5], Wl[5], Bv[5], O, N);
}

// Round 4
// 1165.934 us; speedup vs baseline: 2.2377x; 1.0359x over previous
//
#include <hip/hip_runtime.h>
#include <hip/hip_bf16.h>
#include <hip/hip_fp16.h>

// GIN 3-layer forward, MI355X (gfx950).
// R4: aggregation rewritten for memory-level parallelism — wave-uniform node
// (readfirstlane -> scalar rp/csr loads) + 8 independent row loads in flight.
// Prep kernels (6x wsplit + castx) merged into one block-range dispatch.
// CSR counting-sort build and MFMA GEMM (hi+lo fp16 weights) unchanged.

#define DIN 128
#define DH  256
#define BM  256
#define BN  128
#define BK  64

#define BSHIFT 9
#define BNODES 512
#define MAXB   256
#define PBLK   256

// ------------------------------------------------- CSR build (counting sort)
__global__ __launch_bounds__(1024) void k_bhist(const int* __restrict__ dst,
                                                int* __restrict__ cntMat,
                                                int E, int nbuck, int chunk) {
    __shared__ int h[MAXB];
    for (int i = threadIdx.x; i < nbuck; i += 1024) h[i] = 0;
    __syncthreads();
    const int b = blockIdx.x;
    const int lo = b * chunk, hi = min(lo + chunk, E);
    for (int i = lo + (int)threadIdx.x; i < hi; i += 1024)
        atomicAdd(&h[dst[i] >> BSHIFT], 1);
    __syncthreads();
    for (int i = threadIdx.x; i < nbuck; i += 1024) cntMat[b * nbuck + i] = h[i];
}

__global__ __launch_bounds__(256) void k_bscan(const int* __restrict__ cntMat,
                                               int* __restrict__ bbase,
                                               int* __restrict__ baseMat,
                                               int nbuck, int E) {
    __shared__ int tot[MAXB];
    __shared__ int base[MAXB + 1];
    const int k = threadIdx.x;
    if (k < nbuck) {
        int s = 0;
        for (int b = 0; b < PBLK; ++b) s += cntMat[b * nbuck + k];
        tot[k] = s;
    }
    __syncthreads();
    if (k == 0) {
        int acc = 0;
        for (int i = 0; i < nbuck; ++i) { base[i] = acc; acc += tot[i]; }
        base[nbuck] = acc;
    }
    __syncthreads();
    if (k < nbuck) {
        bbase[k] = base[k];
        int acc = base[k];
        for (int b = 0; b < PBLK; ++b) { baseMat[b * nbuck + k] = acc; acc += cntMat[b * nbuck + k]; }
    }
    if (k == 0) bbase[nbuck] = E;
}

__global__ __launch_bounds__(1024) void k_bpart(const int* __restrict__ src,
                                                const int* __restrict__ dst,
                                                const int* __restrict__ baseMat,
                                                uint2* __restrict__ pairb,
                                                int E, int nbuck, int chunk) {
    __shared__ int cur[MAXB];
    const int b = blockIdx.x;
    for (int i = threadIdx.x; i < nbuck; i += 1024) cur[i] = baseMat[b * nbuck + i];
    __syncthreads();
    const int lo = b * chunk, hi = min(lo + chunk, E);
    for (int i = lo + (int)threadIdx.x; i < hi; i += 1024) {
        int d = dst[i], s = src[i];
        int pos = atomicAdd(&cur[d >> BSHIFT], 1);
        pairb[pos] = make_uint2((unsigned)d, (unsigned)s);
    }
}

__global__ __launch_bounds__(1024) void k_bcsr(const uint2* __restrict__ pairb,
                                               const int* __restrict__ bbase,
                                               int* __restrict__ rp,
                                               int* __restrict__ csr,
                                               int N, int E) {
    __shared__ int cnt[BNODES];
    __shared__ int cur[BNODES];
    const int k = blockIdx.x;
    const int node0 = k << BSHIFT;
    const int nn = min(BNODES, N - node0);
    const int lo = bbase[k], hi = bbase[k + 1];
    const int tid = threadIdx.x;

    for (int i = tid; i < BNODES; i += 1024) cnt[i] = 0;
    __syncthreads();
    for (int i = lo + tid; i < hi; i += 1024)
        atomicAdd(&cnt[pairb[i].x - node0], 1);
    __syncthreads();

    int v = 0;
    if (tid < BNODES) { v = cnt[tid]; cur[tid] = v; }
    __syncthreads();
    for (int off = 1; off < BNODES; off <<= 1) {
        int add = (tid < BNODES && tid >= off) ? cur[tid - off] : 0;
        __syncthreads();
        if (tid < BNODES) cur[tid] += add;
        __syncthreads();
    }
    if (tid < nn) {
        int start = lo + cur[tid] - v;
        rp[node0 + tid] = start;
        cur[tid] = start;
    }
    __syncthreads();
    for (int i = lo + tid; i < hi; i += 1024) {
        uint2 e = pairb[i];
        int pos = atomicAdd(&cur[e.x - node0], 1);
        csr[pos] = (int)e.y;
    }
    if (k == 0 && tid == 0) rp[N] = E;
}

// ----------------------------------------------- merged prep (wsplit + castx)
struct PrepArgs {
    const float* W[6];
    __half* Wh[6];
    __half* Wl[6];
    const float* x;
    __half* xh;
};

// blocks [0,1408): weight split (W0:128 blocks, W1..5: 256 each)
// blocks [1408, 1408+castBlocks): x -> fp16 (float4 granularity)
__global__ __launch_bounds__(256) void k_prep(PrepArgs a, int n4) {
    int bid = blockIdx.x;
    if (bid < 1408) {
        int w, local;
        if (bid < 128) { w = 0; local = bid; }
        else { w = 1 + (bid - 128) / 256; local = (bid - 128) & 255; }
        const int K = (w == 0) ? DIN : DH;
        int idx = local * 256 + (int)threadIdx.x;
        int k = idx >> 8, c = idx & 255;
        float v = a.W[w][idx];
        __half h = __float2half(v);
        a.Wh[w][c * K + k] = h;
        a.Wl[w][c * K + k] = __float2half(v - __half2float(h));
    } else {
        int i = (bid - 1408) * 256 + (int)threadIdx.x;
        if (i >= n4) return;
        float4 f = *(const float4*)(a.x + (size_t)i * 4);
        __half2 h0 = __floats2half2_rn(f.x, f.y);
        __half2 h1 = __floats2half2_rn(f.z, f.w);
        uint2 o;
        o.x = __builtin_bit_cast(unsigned, h0);
        o.y = __builtin_bit_cast(unsigned, h1);
        *(uint2*)(a.xh + (size_t)i * 4) = o;
    }
}

// ------------------------------------------------------------- aggregation
__device__ __forceinline__ void addrow4(unsigned lo, unsigned hi,
                                        float& a0, float& a1, float& a2, float& a3) {
    __half2 h0 = __builtin_bit_cast(__half2, lo);
    __half2 h1 = __builtin_bit_cast(__half2, hi);
    float2 f0 = __half22float2(h0);
    float2 f1 = __half22float2(h1);
    a0 += f0.x; a1 += f0.y; a2 += f1.x; a3 += f1.y;
}

// out[i] = h[i] + sum_{j->i} h[j]; H fp16 [Mpad x 256]; one wave per node.
// Wave-uniform node -> rp/csr via scalar loads; 8 row loads in flight.
__global__ __launch_bounds__(256) void k_aggh256(const __half* __restrict__ H,
                                                 const int* __restrict__ rp,
                                                 const int* __restrict__ csr,
                                                 __half* __restrict__ out, int n) {
    const int wid = __builtin_amdgcn_readfirstlane((int)(threadIdx.x >> 6));
    const int node = (int)blockIdx.x * 4 + wid;
    if (node >= n) return;
    const int lane = threadIdx.x & 63;
    const __half* Hl = H + (size_t)lane * 4;     // lane's 8B slice of each row
    float a0, a1, a2, a3;
    {
        uint2 v = *(const uint2*)(Hl + (size_t)node * DH);
        a0 = a1 = a2 = a3 = 0.f;
        addrow4(v.x, v.y, a0, a1, a2, a3);       // self (eps=0)
    }
    int p = rp[node];
    const int pe = rp[node + 1];
    for (; p + 8 <= pe; p += 8) {
        int j[8];
#pragma unroll
        for (int i = 0; i < 8; ++i) j[i] = csr[p + i];
        uint2 v[8];
#pragma unroll
        for (int i = 0; i < 8; ++i) v[i] = *(const uint2*)(Hl + (size_t)j[i] * DH);
#pragma unroll
        for (int i = 0; i < 8; ++i) addrow4(v[i].x, v[i].y, a0, a1, a2, a3);
    }
    for (; p < pe; ++p) {
        uint2 v = *(const uint2*)(Hl + (size_t)csr[p] * DH);
        addrow4(v.x, v.y, a0, a1, a2, a3);
    }
    __half2 o0 = __floats2half2_rn(a0, a1);
    __half2 o1 = __floats2half2_rn(a2, a3);
    uint2 ov;
    ov.x = __builtin_bit_cast(unsigned, o0);
    ov.y = __builtin_bit_cast(unsigned, o1);
    *(uint2*)(out + (size_t)node * DH + (size_t)lane * 4) = ov;
}

// layer-1: gather fp16 x-table [N x 128]; 4B/lane.
__global__ __launch_bounds__(256) void k_aggh128(const __half* __restrict__ H,
                                                 const int* __restrict__ rp,
                                                 const int* __restrict__ csr,
                                                 __half* __restrict__ out, int n) {
    const int wid = __builtin_amdgcn_readfirstlane((int)(threadIdx.x >> 6));
    const int node = (int)blockIdx.x * 4 + wid;
    if (node >= n) return;
    const int lane = threadIdx.x & 63;
    const __half* Hl = H + (size_t)lane * 2;
    float a0, a1;
    {
        unsigned v = *(const unsigned*)(Hl + (size_t)node * DIN);
        float2 f = __half22float2(__builtin_bit_cast(__half2, v));
        a0 = f.x; a1 = f.y;
    }
    int p = rp[node];
    const int pe = rp[node + 1];
    for (; p + 8 <= pe; p += 8) {
        int j[8];
#pragma unroll
        for (int i = 0; i < 8; ++i) j[i] = csr[p + i];
        unsigned v[8];
#pragma unroll
        for (int i = 0; i < 8; ++i) v[i] = *(const unsigned*)(Hl + (size_t)j[i] * DIN);
#pragma unroll
        for (int i = 0; i < 8; ++i) {
            float2 f = __half22float2(__builtin_bit_cast(__half2, v[i]));
            a0 += f.x; a1 += f.y;
        }
    }
    for (; p < pe; ++p) {
        unsigned v = *(const unsigned*)(Hl + (size_t)csr[p] * DIN);
        float2 f = __half22float2(__builtin_bit_cast(__half2, v));
        a0 += f.x; a1 += f.y;
    }
    __half2 o = __floats2half2_rn(a0, a1);
    *(unsigned*)(out + (size_t)node * DIN + (size_t)lane * 2) = __builtin_bit_cast(unsigned, o);
}

// ------------------------------------------------------------------- GEMM
typedef __attribute__((ext_vector_type(8))) _Float16 f16x8;
typedef __attribute__((ext_vector_type(4))) float     f32x4;

template<int K, int MODE>
__global__ __launch_bounds__(256, 2) void k_gemm_mfma(
        const __half* __restrict__ A,     // [Mpad x K]
        const __half* __restrict__ Wthi,  // [256 x K]
        const __half* __restrict__ Wtlo,  // [256 x K]
        const float* __restrict__ bias,
        void* __restrict__ Cout, int M) {
    __shared__ __align__(16) __half As[BM * BK];
    __shared__ __align__(16) __half Whs[BN * BK];
    __shared__ __align__(16) __half Wls[BN * BK];

    const int t    = threadIdx.x;
    const int lane = t & 63;
    const int wid  = t >> 6;
    const int wr   = wid >> 1;
    const int wc   = wid & 1;
    const int brow = (int)blockIdx.x * BM;
    const int bcol = (int)blockIdx.y * BN;

    f32x4 acc[8][4] = {};

    for (int k0 = 0; k0 < K; k0 += BK) {
#pragma unroll
        for (int i = 0; i < 8; ++i) {
            int idx = i * 256 + t;
            int r = idx >> 3, q = idx & 7;
            uint4 v = *(const uint4*)(A + (size_t)(brow + r) * K + k0 + q * 8);
            *(uint4*)((char*)As + r * 128 + ((q ^ (r & 7)) << 4)) = v;
        }
#pragma unroll
        for (int i = 0; i < 4; ++i) {
            int idx = i * 256 + t;
            int c = idx >> 3, q = idx & 7;
            size_t go = (size_t)(bcol + c) * K + k0 + q * 8;
            uint4 vh = *(const uint4*)(Wthi + go);
            uint4 vl = *(const uint4*)(Wtlo + go);
            int off = c * 128 + ((q ^ (c & 7)) << 4);
            *(uint4*)((char*)Whs + off) = vh;
            *(uint4*)((char*)Wls + off) = vl;
        }
        __syncthreads();

#pragma unroll
        for (int kk = 0; kk < 2; ++kk) {
            const int qa = kk * 4 + (lane >> 4);
            f16x8 af[8], wh[4], wl[4];
#pragma unroll
            for (int mi = 0; mi < 8; ++mi) {
                int r = wr * 128 + mi * 16 + (lane & 15);
                af[mi] = *(const f16x8*)((const char*)As + r * 128 + ((qa ^ (r & 7)) << 4));
            }
#pragma unroll
            for (int ni = 0; ni < 4; ++ni) {
                int c = wc * 64 + ni * 16 + (lane & 15);
                int off = c * 128 + ((qa ^ (c & 7)) << 4);
                wh[ni] = *(const f16x8*)((const char*)Whs + off);
                wl[ni] = *(const f16x8*)((const char*)Wls + off);
            }
#pragma unroll
            for (int mi = 0; mi < 8; ++mi)
#pragma unroll
                for (int ni = 0; ni < 4; ++ni) {
                    acc[mi][ni] = __builtin_amdgcn_mfma_f32_16x16x32_f16(af[mi], wh[ni], acc[mi][ni], 0, 0, 0);
                    acc[mi][ni] = __builtin_amdgcn_mfma_f32_16x16x32_f16(af[mi], wl[ni], acc[mi][ni], 0, 0, 0);
                }
        }
        __syncthreads();
    }

#pragma unroll
    for (int ni = 0; ni < 4; ++ni) {
        const int c = bcol + wc * 64 + ni * 16 + (lane & 15);
        const float bz = bias[c];
#pragma unroll
        for (int mi = 0; mi < 8; ++mi) {
            const int r0 = brow + wr * 128 + mi * 16 + ((lane >> 4) << 2);
#pragma unroll
            for (int j = 0; j < 4; ++j) {
                int row = r0 + j;
                if (row < M) {
                    float v = acc[mi][ni][j] + bz;
                    if (MODE == 0) {
                        v = fmaxf(v, 0.f);
                        ((__half*)Cout)[(size_t)row * DH + c] = __float2half(v);
                    } else {
                        ((float*)Cout)[(size_t)row * DH + c] = v;
                    }
                }
            }
        }
    }
}

// ------------------------------------------------------------------ launch
static inline size_t align256(size_t x) { return (x + 255) & ~(size_t)255; }

extern "C" void kernel_launch(void* const* d_in, const int* in_sizes, int n_in,
                              void* d_out, int out_size, void* d_ws, size_t ws_size,
                              hipStream_t stream) {
    const float* x   = (const float*)d_in[0];
    const int*   ei  = (const int*)d_in[1];
    const float* W[6]  = {(const float*)d_in[2], (const float*)d_in[4],
                          (const float*)d_in[6], (const float*)d_in[8],
                          (const float*)d_in[10], (const float*)d_in[12]};
    const float* Bv[6] = {(const float*)d_in[3], (const float*)d_in[5],
                          (const float*)d_in[7], (const float*)d_in[9],
                          (const float*)d_in[11], (const float*)d_in[13]};

    const int N = in_sizes[0] / DIN;
    const int E = in_sizes[1] / 2;
    const int Mpad = ((N + BM - 1) / BM) * BM;
    const int* src = ei;
    const int* dst = ei + E;
    const int nbuck  = (N + BNODES - 1) / BNODES;
    const int chunkE = (E + PBLK - 1) / PBLK;

    char* ws = (char*)d_ws;
    __half* A1 = (__half*)ws; ws += align256((size_t)Mpad * DIN * 2);
    __half* Ah = (__half*)ws; ws += align256((size_t)Mpad * DH * 2);
    __half* T  = (__half*)ws; ws += align256((size_t)Mpad * DH * 2);
    __half* Hh = (__half*)ws; ws += align256((size_t)Mpad * DH * 2);
    __half* Xh = (__half*)T;          // alias: T first written after Xh last read
    uint2* pairb = (uint2*)Ah;        // alias: Ah first written after pairb dead
    __half* Wh[6]; __half* Wl[6];
    const int Ks[6] = {DIN, DH, DH, DH, DH, DH};
    for (int i = 0; i < 6; ++i) {
        Wh[i] = (__half*)ws; ws += align256((size_t)Ks[i] * DH * 2);
        Wl[i] = (__half*)ws; ws += align256((size_t)Ks[i] * DH * 2);
    }
    int* cntMat  = (int*)ws; ws += align256((size_t)PBLK * MAXB * 4);
    int* baseMat = (int*)ws; ws += align256((size_t)PBLK * MAXB * 4);
    int* bbase   = (int*)ws; ws += align256((size_t)(MAXB + 1) * 4);
    int* rp      = (int*)ws; ws += align256((size_t)(N + 1) * 4);
    int* csr     = (int*)ws; ws += align256((size_t)E * 4);
    float* O = (float*)d_out;

    // --- merged prep (weight split + x cast) ---
    PrepArgs pa;
    for (int i = 0; i < 6; ++i) { pa.W[i] = W[i]; pa.Wh[i] = Wh[i]; pa.Wl[i] = Wl[i]; }
    pa.x = x; pa.xh = Xh;
    const int n4 = N * DIN / 4;
    const int castBlocks = (n4 + 255) / 256;
    k_prep<<<1408 + castBlocks, 256, 0, stream>>>(pa, n4);

    // --- CSR build (counting sort; no global atomics) ---
    k_bhist<<<PBLK, 1024, 0, stream>>>(dst, cntMat, E, nbuck, chunkE);
    k_bscan<<<1, 256, 0, stream>>>(cntMat, bbase, baseMat, nbuck, E);
    k_bpart<<<PBLK, 1024, 0, stream>>>(src, dst, baseMat, pairb, E, nbuck, chunkE);
    k_bcsr<<<nbuck, 1024, 0, stream>>>(pairb, bbase, rp, csr, N, E);

    const int gAgg = (N + 3) / 4;
    dim3 gGemm(Mpad / BM, DH / BN);

    // --- layer 1 ---
    k_aggh128<<<gAgg, 256, 0, stream>>>(Xh, rp, csr, A1, N);
    k_gemm_mfma<DIN, 0><<<gGemm, 256, 0, stream>>>(A1, Wh[0], Wl[0], Bv[0], T, N);
    k_gemm_mfma<DH,  0><<<gGemm, 256, 0, stream>>>(T,  Wh[1], Wl[1], Bv[1], Hh, N);
    // --- layer 2 ---
    k_aggh256<<<gAgg, 256, 0, stream>>>(Hh, rp, csr, Ah, N);
    k_gemm_mfma<DH,  0><<<gGemm, 256, 0, stream>>>(Ah, Wh[2], Wl[2], Bv[2], T, N);
    k_gemm_mfma<DH,  0><<<gGemm, 256, 0, stream>>>(T,  Wh[3], Wl[3], Bv[3], Hh, N);
    // --- layer 3 ---
    k_aggh256<<<gAgg, 256, 0, stream>>>(Hh, rp, csr, Ah, N);
    k_gemm_mfma<DH,  0><<<gGemm, 256, 0, stream>>>(Ah, Wh[4], Wl[4], Bv[4], T, N);
    k_gemm_mfma<DH,  1><<<gGemm, 256, 0, stream>>>(T,  Wh[5], Wl[5], Bv[5], O, N);
}

// Round 6
// 1134.408 us; speedup vs baseline: 2.2999x; 1.0278x over previous
//
#include <hip/hip_runtime.h>
#include <hip/hip_bf16.h>
#include <hip/hip_fp16.h>

// GIN 3-layer forward, MI355X (gfx950).
// R5 (resubmit; bench never ran): single fp16 W plane (dropped Wlo
// compensation; halves MFMA + W-LDS traffic). Aggs reverted to R3 4x-unroll
// vector form (measured best). Agg is at the L2-miss fabric ceiling
// (~3.9 TB/s fill); byte-reduction (fp8 / src-tiling) held in reserve.

#define DIN 128
#define DH  256
#define BM  256
#define BN  128
#define BK  64

#define BSHIFT 9
#define BNODES 512
#define MAXB   256
#define PBLK   256

// ------------------------------------------------- CSR build (counting sort)
__global__ __launch_bounds__(1024) void k_bhist(const int* __restrict__ dst,
                                                int* __restrict__ cntMat,
                                                int E, int nbuck, int chunk) {
    __shared__ int h[MAXB];
    for (int i = threadIdx.x; i < nbuck; i += 1024) h[i] = 0;
    __syncthreads();
    const int b = blockIdx.x;
    const int lo = b * chunk, hi = min(lo + chunk, E);
    for (int i = lo + (int)threadIdx.x; i < hi; i += 1024)
        atomicAdd(&h[dst[i] >> BSHIFT], 1);
    __syncthreads();
    for (int i = threadIdx.x; i < nbuck; i += 1024) cntMat[b * nbuck + i] = h[i];
}

__global__ __launch_bounds__(256) void k_bscan(const int* __restrict__ cntMat,
                                               int* __restrict__ bbase,
                                               int* __restrict__ baseMat,
                                               int nbuck, int E) {
    __shared__ int tot[MAXB];
    __shared__ int base[MAXB + 1];
    const int k = threadIdx.x;
    if (k < nbuck) {
        int s = 0;
        for (int b = 0; b < PBLK; ++b) s += cntMat[b * nbuck + k];
        tot[k] = s;
    }
    __syncthreads();
    if (k == 0) {
        int acc = 0;
        for (int i = 0; i < nbuck; ++i) { base[i] = acc; acc += tot[i]; }
        base[nbuck] = acc;
    }
    __syncthreads();
    if (k < nbuck) {
        bbase[k] = base[k];
        int acc = base[k];
        for (int b = 0; b < PBLK; ++b) { baseMat[b * nbuck + k] = acc; acc += cntMat[b * nbuck + k]; }
    }
    if (k == 0) bbase[nbuck] = E;
}

__global__ __launch_bounds__(1024) void k_bpart(const int* __restrict__ src,
                                                const int* __restrict__ dst,
                                                const int* __restrict__ baseMat,
                                                uint2* __restrict__ pairb,
                                                int E, int nbuck, int chunk) {
    __shared__ int cur[MAXB];
    const int b = blockIdx.x;
    for (int i = threadIdx.x; i < nbuck; i += 1024) cur[i] = baseMat[b * nbuck + i];
    __syncthreads();
    const int lo = b * chunk, hi = min(lo + chunk, E);
    for (int i = lo + (int)threadIdx.x; i < hi; i += 1024) {
        int d = dst[i], s = src[i];
        int pos = atomicAdd(&cur[d >> BSHIFT], 1);
        pairb[pos] = make_uint2((unsigned)d, (unsigned)s);
    }
}

__global__ __launch_bounds__(1024) void k_bcsr(const uint2* __restrict__ pairb,
                                               const int* __restrict__ bbase,
                                               int* __restrict__ rp,
                                               int* __restrict__ csr,
                                               int N, int E) {
    __shared__ int cnt[BNODES];
    __shared__ int cur[BNODES];
    const int k = blockIdx.x;
    const int node0 = k << BSHIFT;
    const int nn = min(BNODES, N - node0);
    const int lo = bbase[k], hi = bbase[k + 1];
    const int tid = threadIdx.x;

    for (int i = tid; i < BNODES; i += 1024) cnt[i] = 0;
    __syncthreads();
    for (int i = lo + tid; i < hi; i += 1024)
        atomicAdd(&cnt[pairb[i].x - node0], 1);
    __syncthreads();

    int v = 0;
    if (tid < BNODES) { v = cnt[tid]; cur[tid] = v; }
    __syncthreads();
    for (int off = 1; off < BNODES; off <<= 1) {
        int add = (tid < BNODES && tid >= off) ? cur[tid - off] : 0;
        __syncthreads();
        if (tid < BNODES) cur[tid] += add;
        __syncthreads();
    }
    if (tid < nn) {
        int start = lo + cur[tid] - v;
        rp[node0 + tid] = start;
        cur[tid] = start;
    }
    __syncthreads();
    for (int i = lo + tid; i < hi; i += 1024) {
        uint2 e = pairb[i];
        int pos = atomicAdd(&cur[e.x - node0], 1);
        csr[pos] = (int)e.y;
    }
    if (k == 0 && tid == 0) rp[N] = E;
}

// ----------------------------------------------- merged prep (wsplit + castx)
struct PrepArgs {
    const float* W[6];
    __half* Wh[6];
    const float* x;
    __half* xh;
};

// blocks [0,1408): weight transpose+cast (W0:128 blocks, W1..5: 256 each)
// blocks [1408, 1408+castBlocks): x -> fp16
__global__ __launch_bounds__(256) void k_prep(PrepArgs a, int n4) {
    int bid = blockIdx.x;
    if (bid < 1408) {
        int w, local;
        if (bid < 128) { w = 0; local = bid; }
        else { w = 1 + (bid - 128) / 256; local = (bid - 128) & 255; }
        const int K = (w == 0) ? DIN : DH;
        int idx = local * 256 + (int)threadIdx.x;
        int k = idx >> 8, c = idx & 255;
        a.Wh[w][c * K + k] = __float2half(a.W[w][idx]);
    } else {
        int i = (bid - 1408) * 256 + (int)threadIdx.x;
        if (i >= n4) return;
        float4 f = *(const float4*)(a.x + (size_t)i * 4);
        __half2 h0 = __floats2half2_rn(f.x, f.y);
        __half2 h1 = __floats2half2_rn(f.z, f.w);
        uint2 o;
        o.x = __builtin_bit_cast(unsigned, h0);
        o.y = __builtin_bit_cast(unsigned, h1);
        *(uint2*)(a.xh + (size_t)i * 4) = o;
    }
}

// ------------------------------------------------------------- aggregation
__device__ __forceinline__ void addrow4(unsigned lo, unsigned hi,
                                        float& a0, float& a1, float& a2, float& a3) {
    __half2 h0 = __builtin_bit_cast(__half2, lo);
    __half2 h1 = __builtin_bit_cast(__half2, hi);
    float2 f0 = __half22float2(h0);
    float2 f1 = __half22float2(h1);
    a0 += f0.x; a1 += f0.y; a2 += f1.x; a3 += f1.y;
}

// out[i] = h[i] + sum_{j->i} h[j]; H fp16 [Mpad x 256]; one wave per node.
// (R3 form — measured best; the gather saturates the L2-miss fill path.)
__global__ __launch_bounds__(256) void k_aggh256(const __half* __restrict__ H,
                                                 const int* __restrict__ rp,
                                                 const int* __restrict__ csr,
                                                 __half* __restrict__ out, int n) {
    int node = (int)((blockIdx.x * 256 + threadIdx.x) >> 6);
    if (node >= n) return;
    int lane = threadIdx.x & 63;
    const size_t lo4 = (size_t)lane * 4;
    float a0, a1, a2, a3;
    {
        uint2 v = *(const uint2*)(H + (size_t)node * DH + lo4);
        a0 = a1 = a2 = a3 = 0.f;
        addrow4(v.x, v.y, a0, a1, a2, a3);
    }
    int p = rp[node], pe = rp[node + 1];
    for (; p + 3 < pe; p += 4) {
        int j0 = csr[p], j1 = csr[p + 1], j2 = csr[p + 2], j3 = csr[p + 3];
        uint2 v0 = *(const uint2*)(H + (size_t)j0 * DH + lo4);
        uint2 v1 = *(const uint2*)(H + (size_t)j1 * DH + lo4);
        uint2 v2 = *(const uint2*)(H + (size_t)j2 * DH + lo4);
        uint2 v3 = *(const uint2*)(H + (size_t)j3 * DH + lo4);
        addrow4(v0.x, v0.y, a0, a1, a2, a3);
        addrow4(v1.x, v1.y, a0, a1, a2, a3);
        addrow4(v2.x, v2.y, a0, a1, a2, a3);
        addrow4(v3.x, v3.y, a0, a1, a2, a3);
    }
    for (; p < pe; ++p) {
        uint2 v = *(const uint2*)(H + (size_t)csr[p] * DH + lo4);
        addrow4(v.x, v.y, a0, a1, a2, a3);
    }
    __half2 o0 = __floats2half2_rn(a0, a1);
    __half2 o1 = __floats2half2_rn(a2, a3);
    uint2 ov;
    ov.x = __builtin_bit_cast(unsigned, o0);
    ov.y = __builtin_bit_cast(unsigned, o1);
    *(uint2*)(out + (size_t)node * DH + lo4) = ov;
}

// layer-1: gather fp16 x-table [N x 128]; 4B/lane.
__global__ __launch_bounds__(256) void k_aggh128(const __half* __restrict__ H,
                                                 const int* __restrict__ rp,
                                                 const int* __restrict__ csr,
                                                 __half* __restrict__ out, int n) {
    int node = (int)((blockIdx.x * 256 + threadIdx.x) >> 6);
    if (node >= n) return;
    int lane = threadIdx.x & 63;
    const size_t lo2 = (size_t)lane * 2;
    float a0, a1;
    {
        unsigned v = *(const unsigned*)(H + (size_t)node * DIN + lo2);
        float2 f = __half22float2(__builtin_bit_cast(__half2, v));
        a0 = f.x; a1 = f.y;
    }
    int p = rp[node], pe = rp[node + 1];
    for (; p + 3 < pe; p += 4) {
        int j0 = csr[p], j1 = csr[p + 1], j2 = csr[p + 2], j3 = csr[p + 3];
        unsigned v0 = *(const unsigned*)(H + (size_t)j0 * DIN + lo2);
        unsigned v1 = *(const unsigned*)(H + (size_t)j1 * DIN + lo2);
        unsigned v2 = *(const unsigned*)(H + (size_t)j2 * DIN + lo2);
        unsigned v3 = *(const unsigned*)(H + (size_t)j3 * DIN + lo2);
        float2 f0 = __half22float2(__builtin_bit_cast(__half2, v0));
        float2 f1 = __half22float2(__builtin_bit_cast(__half2, v1));
        float2 f2 = __half22float2(__builtin_bit_cast(__half2, v2));
        float2 f3 = __half22float2(__builtin_bit_cast(__half2, v3));
        a0 += f0.x + f1.x + f2.x + f3.x;
        a1 += f0.y + f1.y + f2.y + f3.y;
    }
    for (; p < pe; ++p) {
        unsigned v = *(const unsigned*)(H + (size_t)csr[p] * DIN + lo2);
        float2 f = __half22float2(__builtin_bit_cast(__half2, v));
        a0 += f.x; a1 += f.y;
    }
    __half2 o = __floats2half2_rn(a0, a1);
    *(unsigned*)(out + (size_t)node * DIN + lo2) = __builtin_bit_cast(unsigned, o);
}

// ------------------------------------------------------------------- GEMM
// C[M x 256] = A[M x K](fp16) @ W[K x 256](fp16) + bias; fp32 accumulate.
// BM=256 BN=128 BK=64, 4 waves, wave-tile 128x64. Single W plane (R5):
// per kk: 12 ds_read_b128 + 32 MFMA. XOR-swizzled LDS (conflict-free).
typedef __attribute__((ext_vector_type(8))) _Float16 f16x8;
typedef __attribute__((ext_vector_type(4))) float     f32x4;

template<int K, int MODE>
__global__ __launch_bounds__(256, 2) void k_gemm_mfma(
        const __half* __restrict__ A,    // [Mpad x K]
        const __half* __restrict__ Wt,   // [256 x K] (transposed W)
        const float* __restrict__ bias,
        void* __restrict__ Cout, int M) {
    __shared__ __align__(16) __half As[BM * BK];   // 32 KB
    __shared__ __align__(16) __half Ws[BN * BK];   // 16 KB

    const int t    = threadIdx.x;
    const int lane = t & 63;
    const int wid  = t >> 6;
    const int wr   = wid >> 1;
    const int wc   = wid & 1;
    const int brow = (int)blockIdx.x * BM;
    const int bcol = (int)blockIdx.y * BN;

    f32x4 acc[8][4] = {};

    for (int k0 = 0; k0 < K; k0 += BK) {
#pragma unroll
        for (int i = 0; i < 8; ++i) {
            int idx = i * 256 + t;
            int r = idx >> 3, q = idx & 7;
            uint4 v = *(const uint4*)(A + (size_t)(brow + r) * K + k0 + q * 8);
            *(uint4*)((char*)As + r * 128 + ((q ^ (r & 7)) << 4)) = v;
        }
#pragma unroll
        for (int i = 0; i < 4; ++i) {
            int idx = i * 256 + t;
            int c = idx >> 3, q = idx & 7;
            uint4 vh = *(const uint4*)(Wt + (size_t)(bcol + c) * K + k0 + q * 8);
            *(uint4*)((char*)Ws + c * 128 + ((q ^ (c & 7)) << 4)) = vh;
        }
        __syncthreads();

#pragma unroll
        for (int kk = 0; kk < 2; ++kk) {
            const int qa = kk * 4 + (lane >> 4);
            f16x8 af[8], wf[4];
#pragma unroll
            for (int mi = 0; mi < 8; ++mi) {
                int r = wr * 128 + mi * 16 + (lane & 15);
                af[mi] = *(const f16x8*)((const char*)As + r * 128 + ((qa ^ (r & 7)) << 4));
            }
#pragma unroll
            for (int ni = 0; ni < 4; ++ni) {
                int c = wc * 64 + ni * 16 + (lane & 15);
                wf[ni] = *(const f16x8*)((const char*)Ws + c * 128 + ((qa ^ (c & 7)) << 4));
            }
#pragma unroll
            for (int mi = 0; mi < 8; ++mi)
#pragma unroll
                for (int ni = 0; ni < 4; ++ni)
                    acc[mi][ni] = __builtin_amdgcn_mfma_f32_16x16x32_f16(af[mi], wf[ni], acc[mi][ni], 0, 0, 0);
        }
        __syncthreads();
    }

#pragma unroll
    for (int ni = 0; ni < 4; ++ni) {
        const int c = bcol + wc * 64 + ni * 16 + (lane & 15);
        const float bz = bias[c];
#pragma unroll
        for (int mi = 0; mi < 8; ++mi) {
            const int r0 = brow + wr * 128 + mi * 16 + ((lane >> 4) << 2);
#pragma unroll
            for (int j = 0; j < 4; ++j) {
                int row = r0 + j;
                if (row < M) {
                    float v = acc[mi][ni][j] + bz;
                    if (MODE == 0) {
                        v = fmaxf(v, 0.f);
                        ((__half*)Cout)[(size_t)row * DH + c] = __float2half(v);
                    } else {
                        ((float*)Cout)[(size_t)row * DH + c] = v;
                    }
                }
            }
        }
    }
}

// ------------------------------------------------------------------ launch
static inline size_t align256(size_t x) { return (x + 255) & ~(size_t)255; }

extern "C" void kernel_launch(void* const* d_in, const int* in_sizes, int n_in,
                              void* d_out, int out_size, void* d_ws, size_t ws_size,
                              hipStream_t stream) {
    const float* x   = (const float*)d_in[0];
    const int*   ei  = (const int*)d_in[1];
    const float* W[6]  = {(const float*)d_in[2], (const float*)d_in[4],
                          (const float*)d_in[6], (const float*)d_in[8],
                          (const float*)d_in[10], (const float*)d_in[12]};
    const float* Bv[6] = {(const float*)d_in[3], (const float*)d_in[5],
                          (const float*)d_in[7], (const float*)d_in[9],
                          (const float*)d_in[11], (const float*)d_in[13]};

    const int N = in_sizes[0] / DIN;
    const int E = in_sizes[1] / 2;
    const int Mpad = ((N + BM - 1) / BM) * BM;
    const int* src = ei;
    const int* dst = ei + E;
    const int nbuck  = (N + BNODES - 1) / BNODES;
    const int chunkE = (E + PBLK - 1) / PBLK;

    char* ws = (char*)d_ws;
    __half* A1 = (__half*)ws; ws += align256((size_t)Mpad * DIN * 2);
    __half* Ah = (__half*)ws; ws += align256((size_t)Mpad * DH * 2);
    __half* T  = (__half*)ws; ws += align256((size_t)Mpad * DH * 2);
    __half* Hh = (__half*)ws; ws += align256((size_t)Mpad * DH * 2);
    __half* Xh = (__half*)T;          // alias: T first written after Xh last read
    uint2* pairb = (uint2*)Ah;        // alias: Ah first written after pairb dead
    __half* Wh[6];
    const int Ks[6] = {DIN, DH, DH, DH, DH, DH};
    for (int i = 0; i < 6; ++i) {
        Wh[i] = (__half*)ws; ws += align256((size_t)Ks[i] * DH * 2);
    }
    int* cntMat  = (int*)ws; ws += align256((size_t)PBLK * MAXB * 4);
    int* baseMat = (int*)ws; ws += align256((size_t)PBLK * MAXB * 4);
    int* bbase   = (int*)ws; ws += align256((size_t)(MAXB + 1) * 4);
    int* rp      = (int*)ws; ws += align256((size_t)(N + 1) * 4);
    int* csr     = (int*)ws; ws += align256((size_t)E * 4);
    float* O = (float*)d_out;

    // --- merged prep (weight transpose/cast + x cast) ---
    PrepArgs pa;
    for (int i = 0; i < 6; ++i) { pa.W[i] = W[i]; pa.Wh[i] = Wh[i]; }
    pa.x = x; pa.xh = Xh;
    const int n4 = N * DIN / 4;
    const int castBlocks = (n4 + 255) / 256;
    k_prep<<<1408 + castBlocks, 256, 0, stream>>>(pa, n4);

    // --- CSR build (counting sort; no global atomics) ---
    k_bhist<<<PBLK, 1024, 0, stream>>>(dst, cntMat, E, nbuck, chunkE);
    k_bscan<<<1, 256, 0, stream>>>(cntMat, bbase, baseMat, nbuck, E);
    k_bpart<<<PBLK, 1024, 0, stream>>>(src, dst, baseMat, pairb, E, nbuck, chunkE);
    k_bcsr<<<nbuck, 1024, 0, stream>>>(pairb, bbase, rp, csr, N, E);

    const int gAgg = (N + 3) / 4;
    dim3 gGemm(Mpad / BM, DH / BN);

    // --- layer 1 ---
    k_aggh128<<<gAgg, 256, 0, stream>>>(Xh, rp, csr, A1, N);
    k_gemm_mfma<DIN, 0><<<gGemm, 256, 0, stream>>>(A1, Wh[0], Bv[0], T, N);
    k_gemm_mfma<DH,  0><<<gGemm, 256, 0, stream>>>(T,  Wh[1], Bv[1], Hh, N);
    // --- layer 2 ---
    k_aggh256<<<gAgg, 256, 0, stream>>>(Hh, rp, csr, Ah, N);
    k_gemm_mfma<DH,  0><<<gGemm, 256, 0, stream>>>(Ah, Wh[2], Bv[2], T, N);
    k_gemm_mfma<DH,  0><<<gGemm, 256, 0, stream>>>(T,  Wh[3], Bv[3], Hh, N);
    // --- layer 3 ---
    k_aggh256<<<gAgg, 256, 0, stream>>>(Hh, rp, csr, Ah, N);
    k_gemm_mfma<DH,  0><<<gGemm, 256, 0, stream>>>(Ah, Wh[4], Bv[4], T, N);
    k_gemm_mfma<DH,  1><<<gGemm, 256, 0, stream>>>(T,  Wh[5], Bv[5], O, N);
}